// Round 6
// baseline (627.347 us; speedup 1.0000x reference)
//
#include <hip/hip_runtime.h>
#include <hip/hip_bf16.h>
#include <math.h>

#define FDIM 512
#define MFD  4096
#define CNUM 20
#define BATCH 2048
#define SMAX 256
#define GKS  16    // gram k-split
#define GBK  64    // gram k-step
#define SKS  4     // skinny k-split (slice = 1024)
#define AJS  4     // attn row-split

typedef __attribute__((ext_vector_type(8))) short bf16x8;
typedef __attribute__((ext_vector_type(4))) float f32x4;

__device__ inline unsigned short f2bf1(float f) {
  union { float f; unsigned u; } a; a.f = f;
  unsigned r = a.u + 0x7fffu + ((a.u >> 16) & 1u);   // RNE
  return (unsigned short)(r >> 16);
}
__device__ inline float bf2f(unsigned short u) {
  union { unsigned u; float f; } a; a.u = ((unsigned)u) << 16; return a.f;
}
__device__ inline float fast_tanh(float x) {
  float cx = fminf(fmaxf(x, -15.f), 15.f);
  float e = __expf(2.f * cx);
  return (e - 1.f) / (e + 1.f);
}
__device__ inline float dot4acc(float4 a, float4 b, float acc) {
  acc = fmaf(a.x, b.x, acc); acc = fmaf(a.y, b.y, acc);
  acc = fmaf(a.z, b.z, acc); acc = fmaf(a.w, b.w, acc);
  return acc;
}
__device__ inline void gload_lds16(const void* g, void* l) {
  __builtin_amdgcn_global_load_lds(
      (const __attribute__((address_space(1))) unsigned int*)g,
      (__attribute__((address_space(3))) unsigned int*)l, 16, 0, 0);
}

// ---------------- fp32 -> bf16 conversion ----------------
__global__ __launch_bounds__(256) void cvt_bf16(const float* __restrict__ in,
                                                unsigned short* __restrict__ out, int n4) {
  int i = blockIdx.x * 256 + threadIdx.x;
  if (i >= n4) return;
  float4 v = ((const float4*)in)[i];
  ((ushort4*)out)[i] = make_ushort4(f2bf1(v.x), f2bf1(v.y), f2bf1(v.z), f2bf1(v.w));
}

// ---------------- bf16 MFMA GEMM: C = act(A @ B^T + bias) ----------------
// 128x128 tile, BK=32, 4 waves. XOR-swizzled 16B LDS slots (src+read, same involution).
template<int ACT, int OUTBF>
__global__ __launch_bounds__(256) void mfma_gemm(const unsigned short* __restrict__ A,
                                                 const unsigned short* __restrict__ B,
                                                 const float* __restrict__ bias,
                                                 float* __restrict__ Cf,
                                                 unsigned short* __restrict__ Cb,
                                                 int M, int N, int K) {
  __shared__ __align__(16) char lds[16384];
  const int t = threadIdx.x, lane = t & 63, w = t >> 6;
  const int wr = w >> 1, wc = w & 1;
  const int m0 = blockIdx.y * 128, n0 = blockIdx.x * 128;

  f32x4 acc[4][4];
#pragma unroll
  for (int m = 0; m < 4; ++m)
#pragma unroll
    for (int n = 0; n < 4; ++n) acc[m][n] = (f32x4){0.f, 0.f, 0.f, 0.f};

  int rS[2], qS[2];
#pragma unroll
  for (int i = 0; i < 2; ++i) {
    int t16 = (w * 2 + i) * 64 + lane;
    rS[i] = t16 >> 2;
    qS[i] = (t16 & 3) ^ ((rS[i] >> 1) & 3);
  }

  for (int k0 = 0; k0 < K; k0 += 32) {
#pragma unroll
    for (int i = 0; i < 2; ++i) {
      gload_lds16(A + (size_t)(m0 + rS[i]) * K + k0 + qS[i] * 8,
                  lds + (w * 2 + i) * 1024);
      gload_lds16(B + (size_t)(n0 + rS[i]) * K + k0 + qS[i] * 8,
                  lds + 8192 + (w * 2 + i) * 1024);
    }
    __syncthreads();

    bf16x8 af[4], bfr[4];
    const int kq = lane >> 4, l15 = lane & 15;
#pragma unroll
    for (int m = 0; m < 4; ++m) {
      int ra = wr * 64 + m * 16 + l15;
      af[m] = *(const bf16x8*)(lds + ra * 64 + ((kq ^ ((ra >> 1) & 3)) << 4));
      int rb = wc * 64 + m * 16 + l15;
      bfr[m] = *(const bf16x8*)(lds + 8192 + rb * 64 + ((kq ^ ((rb >> 1) & 3)) << 4));
    }
#pragma unroll
    for (int m = 0; m < 4; ++m)
#pragma unroll
      for (int n = 0; n < 4; ++n)
        acc[m][n] = __builtin_amdgcn_mfma_f32_16x16x32_bf16(af[m], bfr[n], acc[m][n], 0, 0, 0);
    __syncthreads();
  }

#pragma unroll
  for (int n = 0; n < 4; ++n) {
    int col = n0 + wc * 64 + n * 16 + (lane & 15);
    float bv = bias[col];
#pragma unroll
    for (int m = 0; m < 4; ++m) {
      int rbase = m0 + wr * 64 + m * 16 + ((lane >> 4) << 2);
#pragma unroll
      for (int j = 0; j < 4; ++j) {
        float v = acc[m][n][j] + bv;
        if (ACT == 1) v = fmaxf(v, 0.f);
        if (ACT == 2) v = fast_tanh(v);
        if (OUTBF) Cb[(size_t)(rbase + j) * N + col] = f2bf1(v);
        else       Cf[(size_t)(rbase + j) * N + col] = v;
      }
    }
  }
}

// ---------------- per-class index lists ----------------
__global__ void build_idx(const int* __restrict__ label, int* __restrict__ idx,
                          int* __restrict__ counts) {
  __shared__ int cnt[CNUM];
  int t = threadIdx.x;
  if (t < CNUM) cnt[t] = 0;
  __syncthreads();
  for (int b = t; b < BATCH; b += 256) {
    int c = label[b];
    int p = atomicAdd(&cnt[c], 1);
    idx[c * BATCH + p] = b;
  }
  __syncthreads();
  if (t < CNUM) counts[t] = cnt[t];
}

// -------- per-class gram via MFMA: S_c += G_c(bf16) @ G_c^T, split-K, atomics --------
__global__ __launch_bounds__(256) void gram_mfma(const unsigned short* __restrict__ Gb,
                                                 const int* __restrict__ idx,
                                                 const int* __restrict__ counts,
                                                 float* __restrict__ S) {
  const int c = blockIdx.z, n = counts[c];
  const int tp = blockIdx.y, ti = tp >> 1, tj = tp & 1;
  const int i0 = ti * 128, j0 = tj * 128;
  if (i0 >= n || j0 >= n) return;
  const int* idc = idx + c * BATCH;
  __shared__ __align__(16) char lds[32768];
  const bool same = (ti == tj);
  char* ldsB = same ? lds : (lds + 16384);

  const int t = threadIdx.x, lane = t & 63, w = t >> 6;
  size_t offA[4], offB[4];
#pragma unroll
  for (int q = 0; q < 4; ++q) {
    int t16 = q * 256 + t;
    int r = t16 >> 3, p = t16 & 7;
    int ch = p ^ (r & 7);
    int ia = i0 + r, jb = j0 + r;
    offA[q] = (size_t)idc[ia < n ? ia : 0] * MFD + ch * 8;
    offB[q] = (size_t)idc[jb < n ? jb : 0] * MFD + ch * 8;
  }
  const int kbeg = blockIdx.x * (MFD / GKS);

  f32x4 acc[2][8];
#pragma unroll
  for (int fi = 0; fi < 2; ++fi)
#pragma unroll
    for (int fj = 0; fj < 8; ++fj) acc[fi][fj] = (f32x4){0.f, 0.f, 0.f, 0.f};

  const int l15 = lane & 15, kq = lane >> 4;
  for (int k0 = kbeg; k0 < kbeg + MFD / GKS; k0 += GBK) {
#pragma unroll
    for (int q = 0; q < 4; ++q) {
      gload_lds16(Gb + offA[q] + k0, lds + q * 4096 + w * 1024 + (lane << 4));
      if (!same)
        gload_lds16(Gb + offB[q] + k0, ldsB + q * 4096 + w * 1024 + (lane << 4));
    }
    __syncthreads();
#pragma unroll
    for (int kk = 0; kk < 2; ++kk) {
      bf16x8 a[2], b[8];
#pragma unroll
      for (int fi = 0; fi < 2; ++fi) {
        int r = w * 32 + fi * 16 + l15;
        int sl = (kk * 4 + kq) ^ (r & 7);
        a[fi] = *(const bf16x8*)(lds + r * 128 + sl * 16);
      }
#pragma unroll
      for (int fj = 0; fj < 8; ++fj) {
        int r = fj * 16 + l15;
        int sl = (kk * 4 + kq) ^ (r & 7);
        b[fj] = *(const bf16x8*)(ldsB + r * 128 + sl * 16);
      }
#pragma unroll
      for (int fi = 0; fi < 2; ++fi)
#pragma unroll
        for (int fj = 0; fj < 8; ++fj)
          acc[fi][fj] = __builtin_amdgcn_mfma_f32_16x16x32_bf16(a[fi], b[fj], acc[fi][fj], 0, 0, 0);
    }
    __syncthreads();
  }

  float* Sc = S + (size_t)c * SMAX * SMAX;
#pragma unroll
  for (int fi = 0; fi < 2; ++fi) {
    int ibase = i0 + w * 32 + fi * 16 + (lane >> 4) * 4;
#pragma unroll
    for (int fj = 0; fj < 8; ++fj) {
      int j = j0 + fj * 16 + l15;
#pragma unroll
      for (int jj = 0; jj < 4; ++jj)
        atomicAdd(&Sc[(size_t)(ibase + jj) * SMAX + j], acc[fi][fj][jj]);
    }
  }
}

// ---------- row softmax of S, column-weight accumulate (W pre-zeroed) ----------
__global__ __launch_bounds__(256) void softmax_w2(const float* __restrict__ S,
                                                  const int* __restrict__ counts,
                                                  float* __restrict__ W) {
  const int c = blockIdx.y;
  const int n = counts[c];
  __shared__ float wacc[4][SMAX];
  const int t = threadIdx.x, lane = t & 63, wid = t >> 6;
  for (int j = t; j < 4 * SMAX; j += 256) (&wacc[0][0])[j] = 0.f;
  __syncthreads();
  const float* Sc = S + (size_t)c * SMAX * SMAX;
  for (int i = blockIdx.x * 4 + wid; i < n; i += 32) {
    const float* row = Sc + (size_t)i * SMAX;
    float v[4];
    float m = -INFINITY;
#pragma unroll
    for (int q = 0; q < 4; ++q) {
      int j = lane + q * 64;
      v[q] = (j < n) ? row[j] : -INFINITY;
      m = fmaxf(m, v[q]);
    }
#pragma unroll
    for (int s = 32; s; s >>= 1) m = fmaxf(m, __shfl_xor(m, s));
    float e[4], sum = 0.f;
#pragma unroll
    for (int q = 0; q < 4; ++q) {
      int j = lane + q * 64;
      e[q] = (j < n) ? expf(v[q] - m) : 0.f;
      sum += e[q];
    }
#pragma unroll
    for (int s = 32; s; s >>= 1) sum += __shfl_xor(sum, s);
    float inv = 1.f / sum;
#pragma unroll
    for (int q = 0; q < 4; ++q) {
      int j = lane + q * 64;
      if (j < n) wacc[wid][j] += e[q] * inv;
    }
  }
  __syncthreads();
  for (int j = t; j < SMAX; j += 256) {
    float v = wacc[0][j] + wacc[1][j] + wacc[2][j] + wacc[3][j];
    if (v != 0.f) atomicAdd(&W[c * SMAX + j], v);
  }
}

// ---------- attn[c,:] += (1/n) * sum_{j in slice} w_j * label0b[idc[j], :]  (attn pre-zeroed) ----------
__global__ __launch_bounds__(256) void attn_combine3(const unsigned short* __restrict__ Gb,
                                                     const int* __restrict__ idx,
                                                     const int* __restrict__ counts,
                                                     const float* __restrict__ W,
                                                     float* __restrict__ attn) {
  const int c = blockIdx.z, n = counts[c];
  const int col2 = blockIdx.x * 256 + threadIdx.x;   // ushort2 index
  const int j0 = (n * (int)blockIdx.y) / AJS;
  const int j1 = (n * ((int)blockIdx.y + 1)) / AJS;
  const int* idc = idx + c * BATCH;
  const float* Wc = W + c * SMAX;
  float a0 = 0.f, a1 = 0.f;
  for (int j = j0; j < j1; ++j) {
    float wj = Wc[j];
    ushort2 g = ((const ushort2*)(Gb + (size_t)idc[j] * MFD))[col2];
    a0 = fmaf(wj, bf2f(g.x), a0);
    a1 = fmaf(wj, bf2f(g.y), a1);
  }
  if (j1 > j0) {
    float inv = 1.f / (float)n;
    atomicAdd(&attn[(size_t)c * MFD + col2 * 2],     a0 * inv);
    atomicAdd(&attn[(size_t)c * MFD + col2 * 2 + 1], a1 * inv);
  }
}

// ---------- streaming skinny accumulate: accbuf[o][c] += sum_k Wa[o,k]*Aa[c,k] (+Wb*Ab) ----------
// one wave per (col o, k-slice of MFD/SKS); wave shuffle-reduce; per-class atomicAdd.
template<int TWO>
__global__ __launch_bounds__(256) void skinny_acc(const float* __restrict__ Wa,
                                                  const float* __restrict__ Aa,
                                                  const float* __restrict__ Wb,
                                                  const float* __restrict__ Ab,
                                                  float* __restrict__ accbuf) {
  const int t = threadIdx.x, lane = t & 63, wid = t >> 6;
  const int o = blockIdx.x * 4 + wid;
  const int kb4 = blockIdx.y * (MFD / 4 / SKS);   // float4 units
  const float4* W4a = (const float4*)Wa + (size_t)o * (MFD / 4) + kb4;
  const float4* W4b = (const float4*)Wb + (size_t)o * (MFD / 4) + kb4;
  const float4* A4a = (const float4*)Aa + kb4;
  const float4* A4b = (const float4*)Ab + kb4;
  float acc[CNUM] = {};
#pragma unroll
  for (int i = 0; i < MFD / 4 / SKS / 64; ++i) {   // 4 iterations
    int k4 = i * 64 + lane;
    float4 wv = W4a[k4];
    float4 wv2;
    if (TWO) wv2 = W4b[k4];
#pragma unroll
    for (int c = 0; c < CNUM; ++c) {
      acc[c] = dot4acc(A4a[(size_t)c * (MFD / 4) + k4], wv, acc[c]);
      if (TWO) acc[c] = dot4acc(A4b[(size_t)c * (MFD / 4) + k4], wv2, acc[c]);
    }
  }
#pragma unroll
  for (int c = 0; c < CNUM; ++c)
#pragma unroll
    for (int s = 32; s; s >>= 1) acc[c] += __shfl_xor(acc[c], s);
#pragma unroll
  for (int c = 0; c < CNUM; ++c)
    if (lane == c) atomicAdd(&accbuf[(size_t)o * CNUM + c], acc[c]);
}

// ---------- finalize hs: sigmoid(acc + b7 + b8), select by counts ----------
__global__ __launch_bounds__(256) void finalize_hs(const float* __restrict__ accbuf,
                                                   const float* __restrict__ b7,
                                                   const float* __restrict__ b8,
                                                   const int* __restrict__ counts,
                                                   const float* __restrict__ hsin,
                                                   float* __restrict__ hs) {
  const int o = blockIdx.x * 256 + threadIdx.x;
  const float bb = b7[o] + b8[o];
#pragma unroll
  for (int c = 0; c < CNUM; ++c) {
    float v = accbuf[(size_t)o * CNUM + c] + bb;
    v = 1.f / (1.f + __expf(-v));
    hs[(size_t)c * MFD + o] = (counts[c] > 0) ? v : hsin[(size_t)c * MFD + o];
  }
}

// ---------- finalize labels: tanh(acc + b9), select by counts ----------
__global__ __launch_bounds__(256) void finalize_lab(const float* __restrict__ accbuf,
                                                    const float* __restrict__ b9,
                                                    const int* __restrict__ counts,
                                                    const float* __restrict__ labinit,
                                                    float* __restrict__ labels) {
  const int o = blockIdx.x * 256 + threadIdx.x;
  const float bb = b9[o];
#pragma unroll
  for (int c = 0; c < CNUM; ++c) {
    float v = tanhf(accbuf[(size_t)o * CNUM + c] + bb);
    labels[(size_t)c * MFD + o] = (counts[c] > 0) ? v : labinit[(size_t)c * MFD + o];
  }
}

// ---------- row L2 norms (labels only) ----------
__global__ __launch_bounds__(256) void rownorm(const float* __restrict__ X,
                                               float* __restrict__ out, int ncols) {
  const int b = blockIdx.x, t = threadIdx.x;
  const float4* X4 = (const float4*)(X + (size_t)b * ncols);
  float ss = 0.f;
  for (int i = t; i < ncols / 4; i += 256) {
    float4 v = X4[i];
    ss = dot4acc(v, v, ss);
  }
#pragma unroll
  for (int s = 32; s; s >>= 1) ss += __shfl_xor(ss, s);
  __shared__ float red[4];
  const int lane = t & 63, wid = t >> 6;
  if (lane == 0) red[wid] = ss;
  __syncthreads();
  if (t == 0) out[b] = sqrtf(red[0] + red[1] + red[2] + red[3]);
}

// ---------- outs[b,c] with fused row-norm of out_b ----------
__global__ __launch_bounds__(256) void outs_fused(const float* __restrict__ outb,
                                                  const float* __restrict__ labels,
                                                  const float* __restrict__ nl,
                                                  float* __restrict__ dout) {
  const int b = blockIdx.x, t = threadIdx.x;
  const float4* O4 = (const float4*)(outb + (size_t)b * MFD);
  const float4* L4 = (const float4*)labels;
  float acc[CNUM] = {};
  float ss = 0.f;
  for (int i = t; i < MFD / 4; i += 256) {
    float4 ov = O4[i];
    ss = dot4acc(ov, ov, ss);
#pragma unroll
    for (int c = 0; c < CNUM; ++c)
      acc[c] = dot4acc(ov, L4[(size_t)c * (MFD / 4) + i], acc[c]);
  }
#pragma unroll
  for (int s = 32; s; s >>= 1) ss += __shfl_xor(ss, s);
#pragma unroll
  for (int c = 0; c < CNUM; ++c)
#pragma unroll
    for (int s = 32; s; s >>= 1) acc[c] += __shfl_xor(acc[c], s);
  __shared__ float red[4][CNUM + 1];
  const int lane = t & 63, wid = t >> 6;
  if (lane == 0) {
#pragma unroll
    for (int c = 0; c < CNUM; ++c) red[wid][c] = acc[c];
    red[wid][CNUM] = ss;
  }
  __syncthreads();
  if (t < CNUM) {
    float v = red[0][t] + red[1][t] + red[2][t] + red[3][t];
    float nrm = sqrtf(red[0][CNUM] + red[1][CNUM] + red[2][CNUM] + red[3][CNUM]);
    float d = fmaxf(nrm * nl[t], 1e-8f);
    dout[(size_t)b * CNUM + t] = v / d;
  }
}

// ---------- ls rows ----------
__global__ __launch_bounds__(256) void ls_kernel(const float* __restrict__ labels,
                                                 const float* __restrict__ W5,
                                                 const float* __restrict__ b5,
                                                 float* __restrict__ dout) {
  const int c1 = blockIdx.x, t = threadIdx.x;
  __shared__ float lrow[MFD];
  for (int i = t; i < MFD; i += 256) lrow[i] = labels[(size_t)c1 * MFD + i];
  __syncthreads();
  const int lane = t & 63, wid = t >> 6;
  for (int c2 = wid; c2 < CNUM; c2 += 4) {
    const float4* w = (const float4*)(W5 + (size_t)c2 * MFD);
    float acc = 0.f;
    for (int i = lane; i < MFD / 4; i += 64)
      acc = dot4acc(*(const float4*)&lrow[i * 4], w[i], acc);
#pragma unroll
    for (int s = 32; s; s >>= 1) acc += __shfl_xor(acc, s);
    if (lane == 0)
      dout[(size_t)(BATCH + c1) * CNUM + c2] = tanhf(acc + b5[c2]);
  }
}

extern "C" void kernel_launch(void* const* d_in, const int* in_sizes, int n_in,
                              void* d_out, int out_size, void* d_ws, size_t ws_size,
                              hipStream_t stream) {
  const float* x    = (const float*)d_in[0];
  const int*   lab  = (const int*)d_in[1];
  const float* W1 = (const float*)d_in[2];  const float* b1 = (const float*)d_in[3];
  const float* W2 = (const float*)d_in[4];  const float* b2 = (const float*)d_in[5];
  const float* W3 = (const float*)d_in[6];  const float* b3 = (const float*)d_in[7];
  const float* W4 = (const float*)d_in[8];  const float* b4 = (const float*)d_in[9];
  const float* W5 = (const float*)d_in[10]; const float* b5 = (const float*)d_in[11];
  const float* W7 = (const float*)d_in[12]; const float* b7 = (const float*)d_in[13];
  const float* W8 = (const float*)d_in[14]; const float* b8 = (const float*)d_in[15];
  const float* W9 = (const float*)d_in[16]; const float* b9 = (const float*)d_in[17];
  const float* hs_init  = (const float*)d_in[18];
  const float* lab_init = (const float*)d_in[19];
  float* out = (float*)d_out;

  char* base = (char*)d_ws;
  size_t off = 0;
  auto alloc = [&](size_t bytes) { char* p = base + off; off += (bytes + 255) & ~(size_t)255; return p; };

  unsigned short* xb  = (unsigned short*)alloc((size_t)BATCH * FDIM * 2);
  unsigned short* h1b = (unsigned short*)alloc((size_t)BATCH * FDIM * 2);
  unsigned short* h2b = (unsigned short*)alloc((size_t)BATCH * FDIM * 2);
  unsigned short* W1b = (unsigned short*)alloc((size_t)FDIM * FDIM * 2);
  unsigned short* W2b = (unsigned short*)alloc((size_t)FDIM * FDIM * 2);
  unsigned short* W3b = (unsigned short*)alloc((size_t)MFD * FDIM * 2);
  unsigned short* W4b = (unsigned short*)alloc((size_t)MFD * FDIM * 2);
  unsigned short* label0b = (unsigned short*)alloc((size_t)BATCH * MFD * 2);
  float* outb   = (float*)alloc((size_t)BATCH * MFD * 4);
  float* S      = (float*)alloc((size_t)CNUM * SMAX * SMAX * 4);   // contiguous: S, wsum, attn
  float* wsum   = (float*)alloc((size_t)CNUM * SMAX * 4);
  float* attn   = (float*)alloc((size_t)CNUM * MFD * 4);
  float* accA   = (float*)alloc((size_t)MFD * CNUM * 4);           // contiguous: accA, accB
  float* accB   = (float*)alloc((size_t)MFD * CNUM * 4);
  float* hsbuf  = (float*)alloc((size_t)CNUM * MFD * 4);
  float* labels = (float*)alloc((size_t)CNUM * MFD * 4);
  float* nl     = (float*)alloc(64 * 4);
  int* idx      = (int*)alloc((size_t)CNUM * BATCH * 4);
  int* counts   = (int*)alloc(64 * 4);

  // --- fp32 -> bf16 conversions ---
  cvt_bf16<<<(BATCH * FDIM / 4 + 255) / 256, 256, 0, stream>>>(x,  xb,  BATCH * FDIM / 4);
  cvt_bf16<<<(FDIM * FDIM / 4 + 255) / 256, 256, 0, stream>>>(W1, W1b, FDIM * FDIM / 4);
  cvt_bf16<<<(FDIM * FDIM / 4 + 255) / 256, 256, 0, stream>>>(W2, W2b, FDIM * FDIM / 4);
  cvt_bf16<<<(MFD * FDIM / 4 + 255) / 256, 256, 0, stream>>>(W3, W3b, MFD * FDIM / 4);
  cvt_bf16<<<(MFD * FDIM / 4 + 255) / 256, 256, 0, stream>>>(W4, W4b, MFD * FDIM / 4);

  // --- MLP via bf16 MFMA ---
  mfma_gemm<1, 1><<<dim3(FDIM / 128, BATCH / 128), 256, 0, stream>>>(xb,  W1b, b1, nullptr, h1b, BATCH, FDIM, FDIM);
  mfma_gemm<1, 1><<<dim3(FDIM / 128, BATCH / 128), 256, 0, stream>>>(h1b, W2b, b2, nullptr, h2b, BATCH, FDIM, FDIM);
  mfma_gemm<2, 1><<<dim3(MFD / 128, BATCH / 128), 256, 0, stream>>>(h2b, W3b, b3, nullptr, label0b, BATCH, MFD, FDIM);
  mfma_gemm<2, 0><<<dim3(MFD / 128, BATCH / 128), 256, 0, stream>>>(h2b, W4b, b4, outb,   nullptr,  BATCH, MFD, FDIM);

  // --- attention path ---
  build_idx<<<1, 256, 0, stream>>>(lab, idx, counts);
  // zero S + wsum + attn (contiguous) and accA + accB (contiguous)
  hipMemsetAsync(S, 0, (size_t)CNUM * SMAX * SMAX * 4 + (size_t)CNUM * SMAX * 4 + (size_t)CNUM * MFD * 4, stream);
  hipMemsetAsync(accA, 0, (size_t)MFD * CNUM * 8, stream);
  gram_mfma<<<dim3(GKS, 4, CNUM), 256, 0, stream>>>(label0b, idx, counts, S);
  softmax_w2<<<dim3(8, CNUM), 256, 0, stream>>>(S, counts, wsum);
  attn_combine3<<<dim3(MFD / 512, AJS, CNUM), 256, 0, stream>>>(label0b, idx, counts, wsum, attn);

  // --- skinny GEMMs as high-TLP streaming reductions ---
  skinny_acc<1><<<dim3(MFD / 4, SKS), 256, 0, stream>>>(W7, attn, W8, hs_init, accA);
  finalize_hs<<<MFD / 256, 256, 0, stream>>>(accA, b7, b8, counts, hs_init, hsbuf);
  skinny_acc<0><<<dim3(MFD / 4, SKS), 256, 0, stream>>>(W9, hsbuf, nullptr, nullptr, accB);
  finalize_lab<<<MFD / 256, 256, 0, stream>>>(accB, b9, counts, lab_init, labels);

  // --- outputs ---
  rownorm<<<CNUM, 256, 0, stream>>>(labels, nl, MFD);
  outs_fused<<<BATCH, 256, 0, stream>>>(outb, labels, nl, out);
  ls_kernel<<<CNUM, 256, 0, stream>>>(labels, W5, b5, out);
}

// Round 11
// 513.616 us; speedup vs baseline: 1.2214x; 1.2214x over previous
//
#include <hip/hip_runtime.h>
#include <hip/hip_bf16.h>
#include <math.h>

#define FDIM 512
#define MFD  4096
#define CNUM 20
#define BATCH 2048
#define SMAX 256
#define GKS  16    // gram k-split
#define GBK  64    // gram k-step
#define SKS2 4     // skinny k-split (slice = 1024, staged in 4 x 256 phases)
#define AJS  4     // attn row-split

typedef __attribute__((ext_vector_type(8))) short bf16x8;
typedef __attribute__((ext_vector_type(4))) float f32x4;

__device__ inline unsigned short f2bf1(float f) {
  union { float f; unsigned u; } a; a.f = f;
  unsigned r = a.u + 0x7fffu + ((a.u >> 16) & 1u);   // RNE
  return (unsigned short)(r >> 16);
}
__device__ inline float bf2f(unsigned short u) {
  union { unsigned u; float f; } a; a.u = ((unsigned)u) << 16; return a.f;
}
__device__ inline float fast_tanh(float x) {
  float cx = fminf(fmaxf(x, -15.f), 15.f);
  float e = __expf(2.f * cx);
  return (e - 1.f) / (e + 1.f);
}
__device__ inline float dot4acc(float4 a, float4 b, float acc) {
  acc = fmaf(a.x, b.x, acc); acc = fmaf(a.y, b.y, acc);
  acc = fmaf(a.z, b.z, acc); acc = fmaf(a.w, b.w, acc);
  return acc;
}
__device__ inline void gload_lds16(const void* g, void* l) {
  __builtin_amdgcn_global_load_lds(
      (const __attribute__((address_space(1))) unsigned int*)g,
      (__attribute__((address_space(3))) unsigned int*)l, 16, 0, 0);
}

// ---------------- fused fp32 -> bf16 conversion (x, W1, W2, W3, W4 in one launch) ----------------
__global__ __launch_bounds__(256) void cvt_all(const float* __restrict__ x,
                                               const float* __restrict__ W1,
                                               const float* __restrict__ W2,
                                               const float* __restrict__ W3,
                                               const float* __restrict__ W4,
                                               unsigned short* __restrict__ xb,
                                               unsigned short* __restrict__ W1b,
                                               unsigned short* __restrict__ W2b,
                                               unsigned short* __restrict__ W3b,
                                               unsigned short* __restrict__ W4b) {
  const int N0 = BATCH * FDIM / 4;   // 262144
  const int NW = FDIM * FDIM / 4;    // 65536
  const int NB = MFD * FDIM / 4;     // 524288
  int i = blockIdx.x * 256 + threadIdx.x;
  const float* src; unsigned short* dst; int j;
  if (i < N0)                    { src = x;  dst = xb;  j = i; }
  else if (i < N0 + NW)          { src = W1; dst = W1b; j = i - N0; }
  else if (i < N0 + 2 * NW)      { src = W2; dst = W2b; j = i - N0 - NW; }
  else if (i < N0 + 2 * NW + NB) { src = W3; dst = W3b; j = i - N0 - 2 * NW; }
  else                           { src = W4; dst = W4b; j = i - N0 - 2 * NW - NB; }
  float4 v = ((const float4*)src)[j];
  ((ushort4*)dst)[j] = make_ushort4(f2bf1(v.x), f2bf1(v.y), f2bf1(v.z), f2bf1(v.w));
}

// ---------------- bf16 MFMA GEMM: C = act(A @ B^T + bias) ----------------
// 128x128 tile, BK=32, 4 waves. XOR-swizzled 16B LDS slots (src+read, same involution).
template<int ACT, int OUTBF>
__global__ __launch_bounds__(256) void mfma_gemm(const unsigned short* __restrict__ A,
                                                 const unsigned short* __restrict__ B,
                                                 const float* __restrict__ bias,
                                                 float* __restrict__ Cf,
                                                 unsigned short* __restrict__ Cb,
                                                 int M, int N, int K) {
  __shared__ __align__(16) char lds[16384];
  const int t = threadIdx.x, lane = t & 63, w = t >> 6;
  const int wr = w >> 1, wc = w & 1;
  const int m0 = blockIdx.y * 128, n0 = blockIdx.x * 128;

  f32x4 acc[4][4];
#pragma unroll
  for (int m = 0; m < 4; ++m)
#pragma unroll
    for (int n = 0; n < 4; ++n) acc[m][n] = (f32x4){0.f, 0.f, 0.f, 0.f};

  int rS[2], qS[2];
#pragma unroll
  for (int i = 0; i < 2; ++i) {
    int t16 = (w * 2 + i) * 64 + lane;
    rS[i] = t16 >> 2;
    qS[i] = (t16 & 3) ^ ((rS[i] >> 1) & 3);
  }

  for (int k0 = 0; k0 < K; k0 += 32) {
#pragma unroll
    for (int i = 0; i < 2; ++i) {
      gload_lds16(A + (size_t)(m0 + rS[i]) * K + k0 + qS[i] * 8,
                  lds + (w * 2 + i) * 1024);
      gload_lds16(B + (size_t)(n0 + rS[i]) * K + k0 + qS[i] * 8,
                  lds + 8192 + (w * 2 + i) * 1024);
    }
    __syncthreads();

    bf16x8 af[4], bfr[4];
    const int kq = lane >> 4, l15 = lane & 15;
#pragma unroll
    for (int m = 0; m < 4; ++m) {
      int ra = wr * 64 + m * 16 + l15;
      af[m] = *(const bf16x8*)(lds + ra * 64 + ((kq ^ ((ra >> 1) & 3)) << 4));
      int rb = wc * 64 + m * 16 + l15;
      bfr[m] = *(const bf16x8*)(lds + 8192 + rb * 64 + ((kq ^ ((rb >> 1) & 3)) << 4));
    }
#pragma unroll
    for (int m = 0; m < 4; ++m)
#pragma unroll
      for (int n = 0; n < 4; ++n)
        acc[m][n] = __builtin_amdgcn_mfma_f32_16x16x32_bf16(af[m], bfr[n], acc[m][n], 0, 0, 0);
    __syncthreads();
  }

#pragma unroll
  for (int n = 0; n < 4; ++n) {
    int col = n0 + wc * 64 + n * 16 + (lane & 15);
    float bv = bias[col];
#pragma unroll
    for (int m = 0; m < 4; ++m) {
      int rbase = m0 + wr * 64 + m * 16 + ((lane >> 4) << 2);
#pragma unroll
      for (int j = 0; j < 4; ++j) {
        float v = acc[m][n][j] + bv;
        if (ACT == 1) v = fmaxf(v, 0.f);
        if (ACT == 2) v = fast_tanh(v);
        if (OUTBF) Cb[(size_t)(rbase + j) * N + col] = f2bf1(v);
        else       Cf[(size_t)(rbase + j) * N + col] = v;
      }
    }
  }
}

// ---------------- per-class index lists ----------------
__global__ void build_idx(const int* __restrict__ label, int* __restrict__ idx,
                          int* __restrict__ counts) {
  __shared__ int cnt[CNUM];
  int t = threadIdx.x;
  if (t < CNUM) cnt[t] = 0;
  __syncthreads();
  for (int b = t; b < BATCH; b += 256) {
    int c = label[b];
    int p = atomicAdd(&cnt[c], 1);
    idx[c * BATCH + p] = b;
  }
  __syncthreads();
  if (t < CNUM) counts[t] = cnt[t];
}

// -------- per-class gram via MFMA: S_c += G_c(bf16) @ G_c^T, split-K, atomics --------
__global__ __launch_bounds__(256) void gram_mfma(const unsigned short* __restrict__ Gb,
                                                 const int* __restrict__ idx,
                                                 const int* __restrict__ counts,
                                                 float* __restrict__ S) {
  const int c = blockIdx.z, n = counts[c];
  const int tp = blockIdx.y, ti = tp >> 1, tj = tp & 1;
  const int i0 = ti * 128, j0 = tj * 128;
  if (i0 >= n || j0 >= n) return;
  const int* idc = idx + c * BATCH;
  __shared__ __align__(16) char lds[32768];
  const bool same = (ti == tj);
  char* ldsB = same ? lds : (lds + 16384);

  const int t = threadIdx.x, lane = t & 63, w = t >> 6;
  size_t offA[4], offB[4];
#pragma unroll
  for (int q = 0; q < 4; ++q) {
    int t16 = q * 256 + t;
    int r = t16 >> 3, p = t16 & 7;
    int ch = p ^ (r & 7);
    int ia = i0 + r, jb = j0 + r;
    offA[q] = (size_t)idc[ia < n ? ia : 0] * MFD + ch * 8;
    offB[q] = (size_t)idc[jb < n ? jb : 0] * MFD + ch * 8;
  }
  const int kbeg = blockIdx.x * (MFD / GKS);

  f32x4 acc[2][8];
#pragma unroll
  for (int fi = 0; fi < 2; ++fi)
#pragma unroll
    for (int fj = 0; fj < 8; ++fj) acc[fi][fj] = (f32x4){0.f, 0.f, 0.f, 0.f};

  const int l15 = lane & 15, kq = lane >> 4;
  for (int k0 = kbeg; k0 < kbeg + MFD / GKS; k0 += GBK) {
#pragma unroll
    for (int q = 0; q < 4; ++q) {
      gload_lds16(Gb + offA[q] + k0, lds + q * 4096 + w * 1024 + (lane << 4));
      if (!same)
        gload_lds16(Gb + offB[q] + k0, ldsB + q * 4096 + w * 1024 + (lane << 4));
    }
    __syncthreads();
#pragma unroll
    for (int kk = 0; kk < 2; ++kk) {
      bf16x8 a[2], b[8];
#pragma unroll
      for (int fi = 0; fi < 2; ++fi) {
        int r = w * 32 + fi * 16 + l15;
        int sl = (kk * 4 + kq) ^ (r & 7);
        a[fi] = *(const bf16x8*)(lds + r * 128 + sl * 16);
      }
#pragma unroll
      for (int fj = 0; fj < 8; ++fj) {
        int r = fj * 16 + l15;
        int sl = (kk * 4 + kq) ^ (r & 7);
        b[fj] = *(const bf16x8*)(ldsB + r * 128 + sl * 16);
      }
#pragma unroll
      for (int fi = 0; fi < 2; ++fi)
#pragma unroll
        for (int fj = 0; fj < 8; ++fj)
          acc[fi][fj] = __builtin_amdgcn_mfma_f32_16x16x32_bf16(a[fi], b[fj], acc[fi][fj], 0, 0, 0);
    }
    __syncthreads();
  }

  float* Sc = S + (size_t)c * SMAX * SMAX;
#pragma unroll
  for (int fi = 0; fi < 2; ++fi) {
    int ibase = i0 + w * 32 + fi * 16 + (lane >> 4) * 4;
#pragma unroll
    for (int fj = 0; fj < 8; ++fj) {
      int j = j0 + fj * 16 + l15;
#pragma unroll
      for (int jj = 0; jj < 4; ++jj)
        atomicAdd(&Sc[(size_t)(ibase + jj) * SMAX + j], acc[fi][fj][jj]);
    }
  }
}

// ---------- row softmax of S, column-weight accumulate (W pre-zeroed) ----------
__global__ __launch_bounds__(256) void softmax_w2(const float* __restrict__ S,
                                                  const int* __restrict__ counts,
                                                  float* __restrict__ W) {
  const int c = blockIdx.y;
  const int n = counts[c];
  __shared__ float wacc[4][SMAX];
  const int t = threadIdx.x, lane = t & 63, wid = t >> 6;
  for (int j = t; j < 4 * SMAX; j += 256) (&wacc[0][0])[j] = 0.f;
  __syncthreads();
  const float* Sc = S + (size_t)c * SMAX * SMAX;
  for (int i = blockIdx.x * 4 + wid; i < n; i += 32) {
    const float* row = Sc + (size_t)i * SMAX;
    float v[4];
    float m = -INFINITY;
#pragma unroll
    for (int q = 0; q < 4; ++q) {
      int j = lane + q * 64;
      v[q] = (j < n) ? row[j] : -INFINITY;
      m = fmaxf(m, v[q]);
    }
#pragma unroll
    for (int s = 32; s; s >>= 1) m = fmaxf(m, __shfl_xor(m, s));
    float e[4], sum = 0.f;
#pragma unroll
    for (int q = 0; q < 4; ++q) {
      int j = lane + q * 64;
      e[q] = (j < n) ? expf(v[q] - m) : 0.f;
      sum += e[q];
    }
#pragma unroll
    for (int s = 32; s; s >>= 1) sum += __shfl_xor(sum, s);
    float inv = 1.f / sum;
#pragma unroll
    for (int q = 0; q < 4; ++q) {
      int j = lane + q * 64;
      if (j < n) wacc[wid][j] += e[q] * inv;
    }
  }
  __syncthreads();
  for (int j = t; j < SMAX; j += 256) {
    float v = wacc[0][j] + wacc[1][j] + wacc[2][j] + wacc[3][j];
    if (v != 0.f) atomicAdd(&W[c * SMAX + j], v);
  }
}

// ---------- attn[c,:] += (1/n) * sum_{j in slice} w_j * label0b[idc[j], :]  (attn pre-zeroed) ----------
__global__ __launch_bounds__(256) void attn_combine3(const unsigned short* __restrict__ Gb,
                                                     const int* __restrict__ idx,
                                                     const int* __restrict__ counts,
                                                     const float* __restrict__ W,
                                                     float* __restrict__ attn) {
  const int c = blockIdx.z, n = counts[c];
  const int col2 = blockIdx.x * 256 + threadIdx.x;   // ushort2 index
  const int j0 = (n * (int)blockIdx.y) / AJS;
  const int j1 = (n * ((int)blockIdx.y + 1)) / AJS;
  const int* idc = idx + c * BATCH;
  const float* Wc = W + c * SMAX;
  float a0 = 0.f, a1 = 0.f;
  for (int j = j0; j < j1; ++j) {
    float wj = Wc[j];
    ushort2 g = ((const ushort2*)(Gb + (size_t)idc[j] * MFD))[col2];
    a0 = fmaf(wj, bf2f(g.x), a0);
    a1 = fmaf(wj, bf2f(g.y), a1);
  }
  if (j1 > j0) {
    float inv = 1.f / (float)n;
    atomicAdd(&attn[(size_t)c * MFD + col2 * 2],     a0 * inv);
    atomicAdd(&attn[(size_t)c * MFD + col2 * 2 + 1], a1 * inv);
  }
}

// ---------- skinny GEMM, LDS-staged: accbuf[o][c] += sum_k Wa[o,k]*Aa[c,k] (+Wb*Ab) ----------
// grid (MFD/16, SKS2). Block: 16 cols (4/wave), k-slice MFD/SKS2=1024 in 4 phases of 256.
// A-slice staged in LDS (shared by 16 cols -> 16x less L2 amplification); acc[20][4] in
// registers across phases so the 480-op butterfly reduce amortizes over 4 phases.
template<int TWO>
__global__ __launch_bounds__(256) void skinny_lds(const float* __restrict__ Wa,
                                                  const float* __restrict__ Aa,
                                                  const float* __restrict__ Wb,
                                                  const float* __restrict__ Ab,
                                                  float* __restrict__ accbuf) {
  __shared__ float As[(TWO ? 2 : 1) * CNUM][256];
  const int t = threadIdx.x, lane = t & 63, wid = t >> 6;
  const int o0 = blockIdx.x * 16 + wid * 4;
  const int NM = TWO ? 2 : 1;
  float acc[CNUM][4] = {};
  for (int ph = 0; ph < 4; ++ph) {
    const int kb = blockIdx.y * (MFD / SKS2) + ph * 256;
    for (int i = t; i < NM * CNUM * 64; i += 256) {
      int m = i / (CNUM * 64);
      int rem = i - m * (CNUM * 64);
      int c = rem >> 6, k4 = rem & 63;
      const float* src = m ? Ab : Aa;
      *(float4*)&As[m * CNUM + c][k4 * 4] =
          *((const float4*)(src + (size_t)c * MFD + kb) + k4);
    }
    __syncthreads();
    float4 wva[4], wvb[4];
#pragma unroll
    for (int oo = 0; oo < 4; ++oo) {
      wva[oo] = *((const float4*)(Wa + (size_t)(o0 + oo) * MFD + kb) + lane);
      if (TWO) wvb[oo] = *((const float4*)(Wb + (size_t)(o0 + oo) * MFD + kb) + lane);
    }
#pragma unroll
    for (int c = 0; c < CNUM; ++c) {
      float4 av = *((const float4*)As[c] + lane);
#pragma unroll
      for (int oo = 0; oo < 4; ++oo) acc[c][oo] = dot4acc(av, wva[oo], acc[c][oo]);
      if (TWO) {
        float4 bv = *((const float4*)As[CNUM + c] + lane);
#pragma unroll
        for (int oo = 0; oo < 4; ++oo) acc[c][oo] = dot4acc(bv, wvb[oo], acc[c][oo]);
      }
    }
    __syncthreads();
  }
#pragma unroll
  for (int c = 0; c < CNUM; ++c)
#pragma unroll
    for (int oo = 0; oo < 4; ++oo)
#pragma unroll
      for (int s = 32; s; s >>= 1) acc[c][oo] += __shfl_xor(acc[c][oo], s);
#pragma unroll
  for (int c = 0; c < CNUM; ++c)
    if (lane == c) {
#pragma unroll
      for (int oo = 0; oo < 4; ++oo)
        atomicAdd(&accbuf[(size_t)(o0 + oo) * CNUM + c], acc[c][oo]);
    }
}

// ---------- finalize hs: sigmoid(acc + b7 + b8), select by counts ----------
__global__ __launch_bounds__(256) void finalize_hs(const float* __restrict__ accbuf,
                                                   const float* __restrict__ b7,
                                                   const float* __restrict__ b8,
                                                   const int* __restrict__ counts,
                                                   const float* __restrict__ hsin,
                                                   float* __restrict__ hs) {
  const int o = blockIdx.x * 256 + threadIdx.x;
  const float bb = b7[o] + b8[o];
#pragma unroll
  for (int c = 0; c < CNUM; ++c) {
    float v = accbuf[(size_t)o * CNUM + c] + bb;
    v = 1.f / (1.f + __expf(-v));
    hs[(size_t)c * MFD + o] = (counts[c] > 0) ? v : hsin[(size_t)c * MFD + o];
  }
}

// ---------- finalize labels: tanh(acc + b9), select by counts ----------
__global__ __launch_bounds__(256) void finalize_lab(const float* __restrict__ accbuf,
                                                    const float* __restrict__ b9,
                                                    const int* __restrict__ counts,
                                                    const float* __restrict__ labinit,
                                                    float* __restrict__ labels) {
  const int o = blockIdx.x * 256 + threadIdx.x;
  const float bb = b9[o];
#pragma unroll
  for (int c = 0; c < CNUM; ++c) {
    float v = tanhf(accbuf[(size_t)o * CNUM + c] + bb);
    labels[(size_t)c * MFD + o] = (counts[c] > 0) ? v : labinit[(size_t)c * MFD + o];
  }
}

// ---------- row L2 norms (labels only) ----------
__global__ __launch_bounds__(256) void rownorm(const float* __restrict__ X,
                                               float* __restrict__ out, int ncols) {
  const int b = blockIdx.x, t = threadIdx.x;
  const float4* X4 = (const float4*)(X + (size_t)b * ncols);
  float ss = 0.f;
  for (int i = t; i < ncols / 4; i += 256) {
    float4 v = X4[i];
    ss = dot4acc(v, v, ss);
  }
#pragma unroll
  for (int s = 32; s; s >>= 1) ss += __shfl_xor(ss, s);
  __shared__ float red[4];
  const int lane = t & 63, wid = t >> 6;
  if (lane == 0) red[wid] = ss;
  __syncthreads();
  if (t == 0) out[b] = sqrtf(red[0] + red[1] + red[2] + red[3]);
}

// ---------- outs[b,c] with fused row-norm of out_b ----------
__global__ __launch_bounds__(256) void outs_fused(const float* __restrict__ outb,
                                                  const float* __restrict__ labels,
                                                  const float* __restrict__ nl,
                                                  float* __restrict__ dout) {
  const int b = blockIdx.x, t = threadIdx.x;
  const float4* O4 = (const float4*)(outb + (size_t)b * MFD);
  const float4* L4 = (const float4*)labels;
  float acc[CNUM] = {};
  float ss = 0.f;
  for (int i = t; i < MFD / 4; i += 256) {
    float4 ov = O4[i];
    ss = dot4acc(ov, ov, ss);
#pragma unroll
    for (int c = 0; c < CNUM; ++c)
      acc[c] = dot4acc(ov, L4[(size_t)c * (MFD / 4) + i], acc[c]);
  }
#pragma unroll
  for (int s = 32; s; s >>= 1) ss += __shfl_xor(ss, s);
#pragma unroll
  for (int c = 0; c < CNUM; ++c)
#pragma unroll
    for (int s = 32; s; s >>= 1) acc[c] += __shfl_xor(acc[c], s);
  __shared__ float red[4][CNUM + 1];
  const int lane = t & 63, wid = t >> 6;
  if (lane == 0) {
#pragma unroll
    for (int c = 0; c < CNUM; ++c) red[wid][c] = acc[c];
    red[wid][CNUM] = ss;
  }
  __syncthreads();
  if (t < CNUM) {
    float v = red[0][t] + red[1][t] + red[2][t] + red[3][t];
    float nrm = sqrtf(red[0][CNUM] + red[1][CNUM] + red[2][CNUM] + red[3][CNUM]);
    float d = fmaxf(nrm * nl[t], 1e-8f);
    dout[(size_t)b * CNUM + t] = v / d;
  }
}

// ---------- ls rows ----------
__global__ __launch_bounds__(256) void ls_kernel(const float* __restrict__ labels,
                                                 const float* __restrict__ W5,
                                                 const float* __restrict__ b5,
                                                 float* __restrict__ dout) {
  const int c1 = blockIdx.x, t = threadIdx.x;
  __shared__ float lrow[MFD];
  for (int i = t; i < MFD; i += 256) lrow[i] = labels[(size_t)c1 * MFD + i];
  __syncthreads();
  const int lane = t & 63, wid = t >> 6;
  for (int c2 = wid; c2 < CNUM; c2 += 4) {
    const float4* w = (const float4*)(W5 + (size_t)c2 * MFD);
    float acc = 0.f;
    for (int i = lane; i < MFD / 4; i += 64)
      acc = dot4acc(*(const float4*)&lrow[i * 4], w[i], acc);
#pragma unroll
    for (int s = 32; s; s >>= 1) acc += __shfl_xor(acc, s);
    if (lane == 0)
      dout[(size_t)(BATCH + c1) * CNUM + c2] = tanhf(acc + b5[c2]);
  }
}

extern "C" void kernel_launch(void* const* d_in, const int* in_sizes, int n_in,
                              void* d_out, int out_size, void* d_ws, size_t ws_size,
                              hipStream_t stream) {
  const float* x    = (const float*)d_in[0];
  const int*   lab  = (const int*)d_in[1];
  const float* W1 = (const float*)d_in[2];  const float* b1 = (const float*)d_in[3];
  const float* W2 = (const float*)d_in[4];  const float* b2 = (const float*)d_in[5];
  const float* W3 = (const float*)d_in[6];  const float* b3 = (const float*)d_in[7];
  const float* W4 = (const float*)d_in[8];  const float* b4 = (const float*)d_in[9];
  const float* W5 = (const float*)d_in[10]; const float* b5 = (const float*)d_in[11];
  const float* W7 = (const float*)d_in[12]; const float* b7 = (const float*)d_in[13];
  const float* W8 = (const float*)d_in[14]; const float* b8 = (const float*)d_in[15];
  const float* W9 = (const float*)d_in[16]; const float* b9 = (const float*)d_in[17];
  const float* hs_init  = (const float*)d_in[18];
  const float* lab_init = (const float*)d_in[19];
  float* out = (float*)d_out;

  char* base = (char*)d_ws;
  size_t off = 0;
  auto alloc = [&](size_t bytes) { char* p = base + off; off += (bytes + 255) & ~(size_t)255; return p; };

  unsigned short* xb  = (unsigned short*)alloc((size_t)BATCH * FDIM * 2);
  unsigned short* h1b = (unsigned short*)alloc((size_t)BATCH * FDIM * 2);
  unsigned short* h2b = (unsigned short*)alloc((size_t)BATCH * FDIM * 2);
  unsigned short* W1b = (unsigned short*)alloc((size_t)FDIM * FDIM * 2);
  unsigned short* W2b = (unsigned short*)alloc((size_t)FDIM * FDIM * 2);
  unsigned short* W3b = (unsigned short*)alloc((size_t)MFD * FDIM * 2);
  unsigned short* W4b = (unsigned short*)alloc((size_t)MFD * FDIM * 2);
  unsigned short* label0b = (unsigned short*)alloc((size_t)BATCH * MFD * 2);
  float* outb   = (float*)alloc((size_t)BATCH * MFD * 4);
  float* S      = (float*)alloc((size_t)CNUM * SMAX * SMAX * 4);   // contiguous: S, wsum, attn
  float* wsum   = (float*)alloc((size_t)CNUM * SMAX * 4);
  float* attn   = (float*)alloc((size_t)CNUM * MFD * 4);
  float* accA   = (float*)alloc((size_t)MFD * CNUM * 4);           // contiguous: accA, accB
  float* accB   = (float*)alloc((size_t)MFD * CNUM * 4);
  float* hsbuf  = (float*)alloc((size_t)CNUM * MFD * 4);
  float* labels = (float*)alloc((size_t)CNUM * MFD * 4);
  float* nl     = (float*)alloc(64 * 4);
  int* idx      = (int*)alloc((size_t)CNUM * BATCH * 4);
  int* counts   = (int*)alloc(64 * 4);

  // --- fused fp32 -> bf16 conversions (1 launch instead of 5) ---
  {
    const int total4 = BATCH * FDIM / 4 + 2 * (FDIM * FDIM / 4) + 2 * (MFD * FDIM / 4);
    cvt_all<<<total4 / 256, 256, 0, stream>>>(x, W1, W2, W3, W4, xb, W1b, W2b, W3b, W4b);
  }

  // --- MLP via bf16 MFMA ---
  mfma_gemm<1, 1><<<dim3(FDIM / 128, BATCH / 128), 256, 0, stream>>>(xb,  W1b, b1, nullptr, h1b, BATCH, FDIM, FDIM);
  mfma_gemm<1, 1><<<dim3(FDIM / 128, BATCH / 128), 256, 0, stream>>>(h1b, W2b, b2, nullptr, h2b, BATCH, FDIM, FDIM);
  mfma_gemm<2, 1><<<dim3(MFD / 128, BATCH / 128), 256, 0, stream>>>(h2b, W3b, b3, nullptr, label0b, BATCH, MFD, FDIM);
  mfma_gemm<2, 0><<<dim3(MFD / 128, BATCH / 128), 256, 0, stream>>>(h2b, W4b, b4, outb,   nullptr,  BATCH, MFD, FDIM);

  // --- attention path ---
  build_idx<<<1, 256, 0, stream>>>(lab, idx, counts);
  // zero S + wsum + attn (contiguous) and accA + accB (contiguous)
  hipMemsetAsync(S, 0, (size_t)CNUM * SMAX * SMAX * 4 + (size_t)CNUM * SMAX * 4 + (size_t)CNUM * MFD * 4, stream);
  hipMemsetAsync(accA, 0, (size_t)MFD * CNUM * 8, stream);
  gram_mfma<<<dim3(GKS, 4, CNUM), 256, 0, stream>>>(label0b, idx, counts, S);
  softmax_w2<<<dim3(8, CNUM), 256, 0, stream>>>(S, counts, wsum);
  attn_combine3<<<dim3(MFD / 512, AJS, CNUM), 256, 0, stream>>>(label0b, idx, counts, wsum, attn);

  // --- skinny GEMMs: LDS-staged A, 4 cols/wave, k-phased ---
  skinny_lds<1><<<dim3(MFD / 16, SKS2), 256, 0, stream>>>(W7, attn, W8, hs_init, accA);
  finalize_hs<<<MFD / 256, 256, 0, stream>>>(accA, b7, b8, counts, hs_init, hsbuf);
  skinny_lds<0><<<dim3(MFD / 16, SKS2), 256, 0, stream>>>(W9, hsbuf, nullptr, nullptr, accB);
  finalize_lab<<<MFD / 256, 256, 0, stream>>>(accB, b9, counts, lab_init, labels);

  // --- outputs ---
  rownorm<<<CNUM, 256, 0, stream>>>(labels, nl, MFD);
  outs_fused<<<BATCH, 256, 0, stream>>>(outb, labels, nl, out);
  ls_kernel<<<CNUM, 256, 0, stream>>>(labels, W5, b5, out);
}